// Round 3
// baseline (250.362 us; speedup 1.0000x reference)
//
#include <hip/hip_runtime.h>

// out[r] = x[r,:] . colsum(W) + sum(b)
// B=16384, IN_F=2048, OUT_F=8192, all fp32.
//
// colsum via written partials (512 x 16-row chunks) + wide 2-level reduce
// (64 blocks + 8-way atomicAdd), then a wave-per-row GEMV.

#define B_ROWS 16384
#define IN_F   2048
#define OUT_F  8192

constexpr int ROWS_PER_CHUNK = 16;
constexpr int N_CHUNKS   = OUT_F / ROWS_PER_CHUNK;  // 512
constexpr int F4_PER_ROW = IN_F / 4;                // 512

// ws layout (floats):
//   [0, WS_P)         partial colsums, [N_CHUNKS][IN_F]  (4 MB)
//   [WS_P, WS_P+IN_F) final colsum (memset to 0, atomically accumulated)
//   [WS_P+IN_F]       sum(b)
constexpr long WS_P = (long)N_CHUNKS * IN_F;

__global__ __launch_bounds__(256) void colsum_partial(const float* __restrict__ W,
                                                      float* __restrict__ ws) {
    // One block per 16-row chunk, covering the full row width (2 float4/thread).
    const int chunk = blockIdx.x;
    const int t     = threadIdx.x;

    const float4* W4 = reinterpret_cast<const float4*>(W);
    long base = (long)chunk * ROWS_PER_CHUNK * F4_PER_ROW;

    float4 a0 = make_float4(0.f, 0.f, 0.f, 0.f);
    float4 a1 = make_float4(0.f, 0.f, 0.f, 0.f);
#pragma unroll
    for (int r = 0; r < ROWS_PER_CHUNK; ++r) {
        float4 v0 = W4[base + (long)r * F4_PER_ROW + t];
        float4 v1 = W4[base + (long)r * F4_PER_ROW + t + 256];
        a0.x += v0.x; a0.y += v0.y; a0.z += v0.z; a0.w += v0.w;
        a1.x += v1.x; a1.y += v1.y; a1.z += v1.z; a1.w += v1.w;
    }
    float4* P = reinterpret_cast<float4*>(ws);
    P[(long)chunk * F4_PER_ROW + t]       = a0;
    P[(long)chunk * F4_PER_ROW + t + 256] = a1;
}

__global__ __launch_bounds__(256) void reduce_kernel(const float* __restrict__ b,
                                                     float* __restrict__ ws) {
    constexpr int CHUNKS_PER_BLK = N_CHUNKS / 8;  // 64
    if (blockIdx.x == 64) {
        // sum(b) over OUT_F elements.
        __shared__ float red[4];
        float acc = 0.f;
        for (int i = threadIdx.x; i < OUT_F; i += 256) acc += b[i];
#pragma unroll
        for (int off = 32; off > 0; off >>= 1) acc += __shfl_down(acc, off);
        if ((threadIdx.x & 63) == 0) red[threadIdx.x >> 6] = acc;
        __syncthreads();
        if (threadIdx.x == 0) ws[WS_P + IN_F] = red[0] + red[1] + red[2] + red[3];
        return;
    }
    // Block j: columns (j&7)*256..+256, chunks (j>>3)*64..+64.
    const int col = (blockIdx.x & 7) * 256 + threadIdx.x;
    const int c0  = (blockIdx.x >> 3) * CHUNKS_PER_BLK;
    float acc = 0.f;
#pragma unroll
    for (int c = 0; c < CHUNKS_PER_BLK; ++c)
        acc += ws[(long)(c0 + c) * IN_F + col];
    atomicAdd(&ws[WS_P + col], acc);  // 8 contributions per address
}

__global__ __launch_bounds__(256) void gemv_kernel(const float* __restrict__ x,
                                                   const float* __restrict__ ws,
                                                   float* __restrict__ out) {
    // One wave (64 lanes) per output row; 4 rows per block.
    const int wave = threadIdx.x >> 6;
    const int lane = threadIdx.x & 63;
    const int row  = blockIdx.x * 4 + wave;

    const float4* x4 = reinterpret_cast<const float4*>(x + (long)row * IN_F);
    const float4* c4 = reinterpret_cast<const float4*>(ws + WS_P);

    float acc = 0.f;
#pragma unroll
    for (int it = 0; it < IN_F / 4 / 64; ++it) {  // 8 iters
        const int idx = it * 64 + lane;
        float4 xv = x4[idx];
        float4 cv = c4[idx];
        acc += xv.x * cv.x + xv.y * cv.y + xv.z * cv.z + xv.w * cv.w;
    }
#pragma unroll
    for (int off = 32; off > 0; off >>= 1) acc += __shfl_down(acc, off);
    if (lane == 0) out[row] = acc + ws[WS_P + IN_F];
}

extern "C" void kernel_launch(void* const* d_in, const int* in_sizes, int n_in,
                              void* d_out, int out_size, void* d_ws, size_t ws_size,
                              hipStream_t stream) {
    const float* x = (const float*)d_in[0];
    const float* W = (const float*)d_in[1];
    const float* b = (const float*)d_in[2];
    float* out = (float*)d_out;
    float* ws  = (float*)d_ws;

    // Zero the final-colsum accumulator slots (ws is poisoned every call).
    hipMemsetAsync(ws + WS_P, 0, IN_F * sizeof(float), stream);

    colsum_partial<<<N_CHUNKS, 256, 0, stream>>>(W, ws);
    reduce_kernel<<<65, 256, 0, stream>>>(b, ws);
    gemv_kernel<<<B_ROWS / 4, 256, 0, stream>>>(x, ws, out);
}